// Round 7
// baseline (614.210 us; speedup 1.0000x reference)
//
#include <hip/hip_runtime.h>
#include <hip/hip_bf16.h>

#define NN 50000
#define NE 800000
#define IN_CH 64
#define HID 128
#define NL 4
#define LN_EPS 1e-5f

// padded CSR capacity: NE + 7*NN = 1,150,000
#define ECAP 1150000
#define WSCALE 1048576.0f   // 2^20 fixed point for edge-weight sums
#define NGRP 12500          // node groups (4 nodes each) per channel slice

__device__ inline ushort f2bf(float x) {
    __hip_bfloat16 h = __float2bfloat16(x);
    return *(ushort*)&h;
}
__device__ inline float2 bfu(uint u) {
    union { uint i; float f; } a, b;
    a.i = u << 16;
    b.i = u & 0xffff0000u;
    return make_float2(a.f, b.f);
}
__device__ inline void nt_store_f2(float2 v, float2* p) {
    __builtin_nontemporal_store(v.x, &p->x);
    __builtin_nontemporal_store(v.y, &p->y);
}

// ---------------- preprocessing ----------------

__global__ void k_zero(int4* __restrict__ p, int n4) {
    int i = blockIdx.x * blockDim.x + threadIdx.x;
    if (i < n4) p[i] = make_int4(0, 0, 0, 0);
}

// one packed 64-bit atomic per edge: hi32 = count, lo32 = Q20 weight sum.
__global__ void k_deg_cnt(const int* __restrict__ ei, const float* __restrict__ ew,
                          unsigned long long* __restrict__ pk, int* __restrict__ ord) {
    int e = blockIdx.x * blockDim.x + threadIdx.x;
    if (e >= NE) return;
    int d = ei[NE + e];
    unsigned int wq = (unsigned int)__float2uint_rn(ew[e] * WSCALE);
    unsigned long long old = atomicAdd(&pk[d], (1ULL << 32) | (unsigned long long)wq);
    ord[e] = (int)(old >> 32);
}

__global__ void k_dinv(const unsigned long long* __restrict__ pk,
                       float* __restrict__ dinv) {
    int n = blockIdx.x * blockDim.x + threadIdx.x;
    if (n >= NN) return;
    float deg = (float)(unsigned int)(pk[n] & 0xffffffffu) * (1.0f / WSCALE);
    dinv[n] = rsqrtf(deg + 1.0f);
}

// hierarchical scan of padded counts ((cnt+7)&~7) -> rowp (exclusive)
__global__ __launch_bounds__(1024) void k_scan_a(const unsigned long long* __restrict__ pk,
                                                 int* __restrict__ rowp_tmp,
                                                 int* __restrict__ bsum) {
    __shared__ int wsum[16];
    int tid = threadIdx.x;
    int lane = tid & 63, wv = tid >> 6;
    int i = blockIdx.x * 1024 + tid;
    int v = (i < NN) ? (((int)(pk[i] >> 32) + 7) & ~7) : 0;
    int s = v;
#pragma unroll
    for (int off = 1; off < 64; off <<= 1) {
        int t = __shfl_up(s, off, 64);
        if (lane >= off) s += t;
    }
    if (lane == 63) wsum[wv] = s;
    __syncthreads();
    int woff = 0;
    for (int w = 0; w < wv; w++) woff += wsum[w];
    if (i < NN) rowp_tmp[i] = woff + s - v;
    if (tid == 1023) bsum[blockIdx.x] = woff + s;
}

__global__ __launch_bounds__(64) void k_scan_b(const int* __restrict__ bsum,
                                               int* __restrict__ boff,
                                               int* __restrict__ rowp, int nb) {
    int t = threadIdx.x;
    int v = (t < nb) ? bsum[t] : 0;
    int s = v;
#pragma unroll
    for (int off = 1; off < 64; off <<= 1) {
        int u = __shfl_up(s, off, 64);
        if (t >= off) s += u;
    }
    if (t < nb) boff[t] = s - v;
    if (t == 63) rowp[NN] = s;
}

__global__ __launch_bounds__(1024) void k_scan_c(const int* __restrict__ rowp_tmp,
                                                 const int* __restrict__ boff,
                                                 int* __restrict__ rowp) {
    int i = blockIdx.x * 1024 + threadIdx.x;
    if (i < NN) rowp[i] = rowp_tmp[i] + boff[blockIdx.x];
}

// zero only the padding slots: [rowp[n] + cnt[n], rowp[n+1])
__global__ void k_pad(const unsigned long long* __restrict__ pk,
                      const int* __restrict__ rowp, int2* __restrict__ evrec) {
    int n = blockIdx.x * blockDim.x + threadIdx.x;
    if (n >= NN) return;
    int cnt = (int)(pk[n] >> 32);
    int p0 = rowp[n] + cnt, p1 = rowp[n + 1];
    for (int p = p0; p < p1; p++) evrec[p] = make_int2(0, 0);
}

// atomic-free scatter: pos = rowp[d] + ord[e]; one int2 record per edge
__global__ void k_scatter(const int* __restrict__ ei, const float* __restrict__ ew,
                          const float* __restrict__ dinv, const int* __restrict__ rowp,
                          const int* __restrict__ ord, int2* __restrict__ evrec) {
    int e = blockIdx.x * blockDim.x + threadIdx.x;
    if (e >= NE) return;
    int s = ei[e];
    int d = ei[NE + e];
    int pos = rowp[d] + ord[e];
    float v = dinv[s] * ew[e] * dinv[d];
    evrec[pos] = make_int2(s, __float_as_int(v));
}

// ---------------- input projection: h = relu(x @ W_in + b_in) ----------------
__global__ __launch_bounds__(256) void k_inproj(const float* __restrict__ x,
                                                const float* __restrict__ W,
                                                const float* __restrict__ b,
                                                float* __restrict__ h) {
    __shared__ float xs[64][IN_CH];
    int tid = threadIdx.x;
    int cx = tid & 31;
    int ny = tid >> 5;
    int nbase = blockIdx.x * 64;
    const float4* xg = (const float4*)(x + (size_t)nbase * IN_CH);
    float4* xs4 = (float4*)xs;
#pragma unroll
    for (int p = 0; p < 4; p++) {
        int i = p * 256 + tid;
        int row = i >> 4;
        xs4[i] = (nbase + row < NN) ? xg[i] : make_float4(0, 0, 0, 0);
    }
    __syncthreads();
    float4 acc[8];
#pragma unroll
    for (int j = 0; j < 8; j++) acc[j] = make_float4(0, 0, 0, 0);
    const float4* W4 = (const float4*)W;
#pragma unroll 4
    for (int k4 = 0; k4 < IN_CH / 4; k4++) {
        int k = 4 * k4;
        float4 w0 = W4[(k + 0) * 32 + cx];
        float4 w1 = W4[(k + 1) * 32 + cx];
        float4 w2 = W4[(k + 2) * 32 + cx];
        float4 w3 = W4[(k + 3) * 32 + cx];
#pragma unroll
        for (int j = 0; j < 8; j++) {
            float4 hv = *(const float4*)&xs[ny * 8 + j][k];
            acc[j].x += hv.x * w0.x + hv.y * w1.x + hv.z * w2.x + hv.w * w3.x;
            acc[j].y += hv.x * w0.y + hv.y * w1.y + hv.z * w2.y + hv.w * w3.y;
            acc[j].z += hv.x * w0.z + hv.y * w1.z + hv.z * w2.z + hv.w * w3.z;
            acc[j].w += hv.x * w0.w + hv.y * w1.w + hv.z * w2.w + hv.w * w3.w;
        }
    }
    float4 bc = ((const float4*)b)[cx];
    float4* mg = (float4*)h;
#pragma unroll
    for (int j = 0; j < 8; j++) {
        int n = nbase + ny * 8 + j;
        if (n < NN) {
            float4 o;
            o.x = fmaxf(acc[j].x + bc.x, 0.f);
            o.y = fmaxf(acc[j].y + bc.y, 0.f);
            o.z = fmaxf(acc[j].z + bc.z, 0.f);
            o.w = fmaxf(acc[j].w + bc.w, 0.f);
            mg[n * 32 + cx] = o;
        }
    }
}

// ---------------- per-layer GEMM: m(bf16) = h(f32) @ W_l ----------------
__global__ __launch_bounds__(256) void k_gemm(const float* __restrict__ h,
                                              const float* __restrict__ W,
                                              ushort* __restrict__ m) {
    __shared__ float hs[64][HID];
    int tid = threadIdx.x;
    int cx = tid & 31;
    int ny = tid >> 5;
    int nbase = blockIdx.x * 64;
    const float4* hg = (const float4*)(h + (size_t)nbase * HID);
    float4* hs4 = (float4*)hs;
#pragma unroll
    for (int p = 0; p < 8; p++) {
        int i = p * 256 + tid;
        int row = i >> 5;
        hs4[i] = (nbase + row < NN) ? hg[i] : make_float4(0, 0, 0, 0);
    }
    __syncthreads();
    float4 acc[8];
#pragma unroll
    for (int j = 0; j < 8; j++) acc[j] = make_float4(0, 0, 0, 0);
    const float4* W4 = (const float4*)W;
#pragma unroll 4
    for (int k4 = 0; k4 < HID / 4; k4++) {
        int k = 4 * k4;
        float4 w0 = W4[(k + 0) * 32 + cx];
        float4 w1 = W4[(k + 1) * 32 + cx];
        float4 w2 = W4[(k + 2) * 32 + cx];
        float4 w3 = W4[(k + 3) * 32 + cx];
#pragma unroll
        for (int j = 0; j < 8; j++) {
            float4 hv = *(const float4*)&hs[ny * 8 + j][k];
            acc[j].x += hv.x * w0.x + hv.y * w1.x + hv.z * w2.x + hv.w * w3.x;
            acc[j].y += hv.x * w0.y + hv.y * w1.y + hv.z * w2.y + hv.w * w3.y;
            acc[j].z += hv.x * w0.z + hv.y * w1.z + hv.z * w2.z + hv.w * w3.z;
            acc[j].w += hv.x * w0.w + hv.y * w1.w + hv.z * w2.w + hv.w * w3.w;
        }
    }
    ushort4* mg = (ushort4*)m;
#pragma unroll
    for (int j = 0; j < 8; j++) {
        int n = nbase + ny * 8 + j;
        if (n < NN) {
            ushort4 o;
            o.x = f2bf(acc[j].x);
            o.y = f2bf(acc[j].y);
            o.z = f2bf(acc[j].z);
            o.w = f2bf(acc[j].w);
            mg[(size_t)n * 32 + cx] = o;
        }
    }
}

// ---------------- channel-sliced aggregation ----------------
// slice = blockIdx/NGRP (temporal phases; 32-ch slice of m = 3.2 MB, fits L2/XCD).
// wave per node-slice: quarter q gathers edge r+q's 2 channels (uint/lane).
// Output: agg2 (f32, incl. bias) via non-temporal stores + per-slice (sum, sumsq).
__global__ __launch_bounds__(256) void k_gather(const ushort* __restrict__ m,
                                                const int* __restrict__ rowp,
                                                const int2* __restrict__ evrec,
                                                const float* __restrict__ dinv,
                                                const float* __restrict__ cb,
                                                float2* __restrict__ agg2,
                                                float2* __restrict__ part) {
    int bid = blockIdx.x;
    int slice = bid / NGRP;
    int ng = bid - slice * NGRP;
    int lane = threadIdx.x & 63;
    int q = lane >> 4, s16 = lane & 15;
    int n = ng * 4 + (threadIdx.x >> 6);
    const uint* mu = (const uint*)m;
    size_t soff = (size_t)slice * 16 + s16;     // uint (=2ch) index within row
    float dn = dinv[n];
    float2 a0, a1;
    {
        float2 sv = bfu(mu[(size_t)n * 64 + soff]);
        float ss = (q == 0) ? dn * dn : 0.0f;
        float2 cbv = (q == 0) ? ((const float2*)cb)[soff] : make_float2(0.f, 0.f);
        a0.x = ss * sv.x + cbv.x;
        a0.y = ss * sv.y + cbv.y;
        a1 = make_float2(0.f, 0.f);
    }
    int r0 = rowp[n], r1 = rowp[n + 1];          // multiples of 8
    for (int r = r0; r < r1; r += 8) {
        int2 rA = evrec[r + q];
        int2 rB = evrec[r + 4 + q];
        uint gA = mu[(size_t)rA.x * 64 + soff];
        uint gB = mu[(size_t)rB.x * 64 + soff];
        float vA = __int_as_float(rA.y), vB = __int_as_float(rB.y);
        float2 fA = bfu(gA), fB = bfu(gB);
        a0.x += vA * fA.x; a0.y += vA * fA.y;
        a1.x += vB * fB.x; a1.y += vB * fB.y;
    }
    float2 acc = make_float2(a0.x + a1.x, a0.y + a1.y);
    // combine quarters (channels identical across quarters)
    acc.x += __shfl_xor(acc.x, 16, 64); acc.y += __shfl_xor(acc.y, 16, 64);
    acc.x += __shfl_xor(acc.x, 32, 64); acc.y += __shfl_xor(acc.y, 32, 64);
    // per-slice partial stats over 32 channels
    float p1 = acc.x + acc.y;
    float p2 = acc.x * acc.x + acc.y * acc.y;
#pragma unroll
    for (int off = 1; off < 16; off <<= 1) {
        p1 += __shfl_xor(p1, off, 64);
        p2 += __shfl_xor(p2, off, 64);
    }
    if (lane < 16) {
        nt_store_f2(acc, &agg2[(size_t)n * 64 + soff]);
        if (s16 == 0) nt_store_f2(make_float2(p1, p2), &part[(size_t)n * 4 + slice]);
    }
}

// ---------------- LN + relu + residual (in-place h) ----------------
__global__ __launch_bounds__(256) void k_ln(const float2* __restrict__ agg2,
                                            const float2* __restrict__ part,
                                            const float* __restrict__ g,
                                            const float* __restrict__ bb,
                                            float* __restrict__ h) {
    int lane = threadIdx.x & 63;
    int n = blockIdx.x * 4 + (threadIdx.x >> 6);
    float2 av = agg2[(size_t)n * 64 + lane];
    const float4* p4 = (const float4*)(part + (size_t)n * 4);
    float4 pa = p4[0], pb = p4[1];
    float s1 = pa.x + pa.z + pb.x + pb.z;
    float s2 = pa.y + pa.w + pb.y + pb.w;
    float mu = s1 * (1.0f / HID);
    float var = s2 * (1.0f / HID) - mu * mu;
    float rs = rsqrtf(var + LN_EPS);
    float2 gv = ((const float2*)g)[lane];
    float2 bv = ((const float2*)bb)[lane];
    float2* h2 = (float2*)h;
    float2 hv = h2[(size_t)n * 64 + lane];
    float2 o;
    o.x = fmaxf((av.x - mu) * rs * gv.x + bv.x, 0.f) + hv.x;
    o.y = fmaxf((av.y - mu) * rs * gv.y + bv.y, 0.f) + hv.y;
    h2[(size_t)n * 64 + lane] = o;
}

// ---------------- launch ----------------

extern "C" void kernel_launch(void* const* d_in, const int* in_sizes, int n_in,
                              void* d_out, int out_size, void* d_ws, size_t ws_size,
                              hipStream_t stream) {
    const float* x    = (const float*)d_in[0];
    const int*   ei   = (const int*)d_in[1];
    const float* ew   = (const float*)d_in[2];
    const float* W_in = (const float*)d_in[3];
    const float* b_in = (const float*)d_in[4];
    const float* cW   = (const float*)d_in[5];
    const float* cb   = (const float*)d_in[6];
    const float* lg   = (const float*)d_in[7];
    const float* lb   = (const float*)d_in[8];
    float* h = (float*)d_out;

    char* ws = (char*)d_ws;
    unsigned long long* pk = (unsigned long long*)(ws + 0);   // 50000 u64 (cnt|Q20 deg)
    int*    rowp     = (int*)  (ws + 401408);                 // 50001
    int*    rowp_tmp = (int*)  (ws + 602112);
    int*    bsum     = (int*)  (ws + 802816);                 // 64
    int*    boff     = (int*)  (ws + 803072);                 // 64
    int2*   evrec    = (int2*) (ws + 803328);                 // ECAP int2 (9.2 MB)
    ushort* m        = (ushort*)(ws + 10003328);              // 50000*128 bf16 (12.8 MB)
    int*    ord      = (int*)  (ws + 10003328);               // aliases m (dead until gemm)
    float*  dinv     = (float*)(ws + 22803328);               // 50000 f32
    float2* agg2     = (float2*)(ws + 23003328);              // 50000*64 f32x2 (25.6 MB)
    float2* part     = (float2*)(ws + 48603328);              // 50000*4 f32x2 (1.6 MB)

    const int NB = (NN + 1023) / 1024;                        // 49

    k_zero<<<(100000 / 4 + 255) / 256, 256, 0, stream>>>((int4*)pk, 100000 / 4);
    k_deg_cnt<<<(NE + 255) / 256, 256, 0, stream>>>(ei, ew, pk, ord);
    k_dinv<<<(NN + 255) / 256, 256, 0, stream>>>(pk, dinv);
    k_scan_a<<<NB, 1024, 0, stream>>>(pk, rowp_tmp, bsum);
    k_scan_b<<<1, 64, 0, stream>>>(bsum, boff, rowp, NB);
    k_scan_c<<<NB, 1024, 0, stream>>>(rowp_tmp, boff, rowp);
    k_pad<<<(NN + 255) / 256, 256, 0, stream>>>(pk, rowp, evrec);
    k_scatter<<<(NE + 255) / 256, 256, 0, stream>>>(ei, ew, dinv, rowp, ord, evrec);

    k_inproj<<<(NN + 63) / 64, 256, 0, stream>>>(x, W_in, b_in, h);

    for (int l = 0; l < NL; l++) {
        k_gemm<<<(NN + 63) / 64, 256, 0, stream>>>(h, cW + l * HID * HID, m);
        k_gather<<<4 * NGRP, 256, 0, stream>>>(m, rowp, evrec, dinv,
                                               cb + l * HID, agg2, part);
        k_ln<<<NGRP, 256, 0, stream>>>(agg2, part, lg + l * HID, lb + l * HID, h);
    }
}

// Round 8
// 299.371 us; speedup vs baseline: 2.0517x; 2.0517x over previous
//
#include <hip/hip_runtime.h>
#include <hip/hip_bf16.h>

#define NN 50000
#define NE 800000
#define IN_CH 64
#define HID 128
#define NL 4
#define LN_EPS 1e-5f

// padded CSR capacity: NE + 7*NN = 1,150,000
#define ECAP 1150000
#define WSCALE 1048576.0f   // 2^20 fixed point for edge-weight sums
#define VSCALE 32767.0f     // Q15 for packed edge values

typedef __attribute__((ext_vector_type(8))) short s8v;
typedef __attribute__((ext_vector_type(4))) float f4v;

__device__ inline ushort f2bf(float x) {
    __hip_bfloat16 h = __float2bfloat16(x);
    return *(ushort*)&h;
}
__device__ inline float2 bfu(uint u) {
    union { uint i; float f; } a, b;
    a.i = u << 16;
    b.i = u & 0xffff0000u;
    return make_float2(a.f, b.f);
}

// ---------------- preprocessing ----------------

__global__ void k_zero(int4* __restrict__ p, int n4) {
    int i = blockIdx.x * blockDim.x + threadIdx.x;
    if (i < n4) p[i] = make_int4(0, 0, 0, 0);
}

// one packed 64-bit atomic per edge: hi32 = count, lo32 = Q20 weight sum.
__global__ void k_deg_cnt(const int* __restrict__ ei, const float* __restrict__ ew,
                          unsigned long long* __restrict__ pk, int* __restrict__ ord) {
    int e = blockIdx.x * blockDim.x + threadIdx.x;
    if (e >= NE) return;
    int d = ei[NE + e];
    unsigned int wq = (unsigned int)__float2uint_rn(ew[e] * WSCALE);
    unsigned long long old = atomicAdd(&pk[d], (1ULL << 32) | (unsigned long long)wq);
    ord[e] = (int)(old >> 32);
}

// hierarchical scan of padded counts ((cnt+7)&~7) -> rowp (exclusive); fused dinv
__global__ __launch_bounds__(1024) void k_scan_a(const unsigned long long* __restrict__ pk,
                                                 int* __restrict__ rowp_tmp,
                                                 int* __restrict__ bsum,
                                                 float* __restrict__ dinv) {
    __shared__ int wsum[16];
    int tid = threadIdx.x;
    int lane = tid & 63, wv = tid >> 6;
    int i = blockIdx.x * 1024 + tid;
    unsigned long long pv = (i < NN) ? pk[i] : 0ULL;
    if (i < NN) {
        float deg = (float)(unsigned int)(pv & 0xffffffffu) * (1.0f / WSCALE);
        dinv[i] = rsqrtf(deg + 1.0f);
    }
    int v = (((int)(pv >> 32) + 7) & ~7);
    int s = v;
#pragma unroll
    for (int off = 1; off < 64; off <<= 1) {
        int t = __shfl_up(s, off, 64);
        if (lane >= off) s += t;
    }
    if (lane == 63) wsum[wv] = s;
    __syncthreads();
    int woff = 0;
    for (int w = 0; w < wv; w++) woff += wsum[w];
    if (i < NN) rowp_tmp[i] = woff + s - v;
    if (tid == 1023) bsum[blockIdx.x] = woff + s;
}

__global__ __launch_bounds__(64) void k_scan_b(const int* __restrict__ bsum,
                                               int* __restrict__ boff,
                                               int* __restrict__ rowp, int nb) {
    int t = threadIdx.x;
    int v = (t < nb) ? bsum[t] : 0;
    int s = v;
#pragma unroll
    for (int off = 1; off < 64; off <<= 1) {
        int u = __shfl_up(s, off, 64);
        if (t >= off) s += u;
    }
    if (t < nb) boff[t] = s - v;
    if (t == 63) rowp[NN] = s;
}

__global__ __launch_bounds__(1024) void k_scan_c(const int* __restrict__ rowp_tmp,
                                                 const int* __restrict__ boff,
                                                 int* __restrict__ rowp) {
    int i = blockIdx.x * 1024 + threadIdx.x;
    if (i < NN) rowp[i] = rowp_tmp[i] + boff[blockIdx.x];
}

// zero only the padding slots: [rowp[n] + cnt[n], rowp[n+1])
__global__ void k_pad(const unsigned long long* __restrict__ pk,
                      const int* __restrict__ rowp, uint* __restrict__ erec) {
    int n = blockIdx.x * blockDim.x + threadIdx.x;
    if (n >= NN) return;
    int cnt = (int)(pk[n] >> 32);
    int p0 = rowp[n] + cnt, p1 = rowp[n + 1];
    for (int p = p0; p < p1; p++) erec[p] = 0u;
}

// atomic-free scatter: pos = rowp[d] + ord[e]; one u32 record (src<<15 | Q15 val)
__global__ void k_scatter(const int* __restrict__ ei, const float* __restrict__ ew,
                          const float* __restrict__ dinv, const int* __restrict__ rowp,
                          const int* __restrict__ ord, uint* __restrict__ erec) {
    int e = blockIdx.x * blockDim.x + threadIdx.x;
    if (e >= NE) return;
    int s = ei[e];
    int d = ei[NE + e];
    int pos = rowp[d] + ord[e];
    float v = dinv[s] * ew[e] * dinv[d];               // in (0, 1]
    uint q = (uint)__float2int_rn(v * VSCALE);
    erec[pos] = ((uint)s << 15) | q;
}

// ---------------- W repack for MFMA: all layers at once ----------------
// Wp[layer][kc][t][lane][8] bf16: lane holds B[k=kc*32+(lane>>4)*8+j][col=t*16+(lane&15)]
__global__ __launch_bounds__(256) void k_wpack(const float* __restrict__ cW,
                                               ushort* __restrict__ Wp) {
    int gid = blockIdx.x * 256 + threadIdx.x;          // 0 .. 8191
    int lane = gid & 63;
    int t = (gid >> 6) & 7;
    int kc = (gid >> 9) & 3;
    int layer = gid >> 11;
    const float* W = cW + (size_t)layer * HID * HID;
    int kbase = kc * 32 + (lane >> 4) * 8;
    int col = t * 16 + (lane & 15);
    ushort o[8];
#pragma unroll
    for (int j = 0; j < 8; j++) o[j] = f2bf(W[(size_t)(kbase + j) * HID + col]);
    uint4 pk4;
    pk4.x = (uint)o[0] | ((uint)o[1] << 16);
    pk4.y = (uint)o[2] | ((uint)o[3] << 16);
    pk4.z = (uint)o[4] | ((uint)o[5] << 16);
    pk4.w = (uint)o[6] | ((uint)o[7] << 16);
    ((uint4*)Wp)[gid] = pk4;
}

// ---------------- input projection: h = relu(x @ W_in + b_in) ----------------
__global__ __launch_bounds__(256) void k_inproj(const float* __restrict__ x,
                                                const float* __restrict__ W,
                                                const float* __restrict__ b,
                                                float* __restrict__ h) {
    __shared__ float xs[64][IN_CH];
    int tid = threadIdx.x;
    int cx = tid & 31;
    int ny = tid >> 5;
    int nbase = blockIdx.x * 64;
    const float4* xg = (const float4*)(x + (size_t)nbase * IN_CH);
    float4* xs4 = (float4*)xs;
#pragma unroll
    for (int p = 0; p < 4; p++) {
        int i = p * 256 + tid;
        int row = i >> 4;
        xs4[i] = (nbase + row < NN) ? xg[i] : make_float4(0, 0, 0, 0);
    }
    __syncthreads();
    float4 acc[8];
#pragma unroll
    for (int j = 0; j < 8; j++) acc[j] = make_float4(0, 0, 0, 0);
    const float4* W4 = (const float4*)W;
#pragma unroll 4
    for (int k4 = 0; k4 < IN_CH / 4; k4++) {
        int k = 4 * k4;
        float4 w0 = W4[(k + 0) * 32 + cx];
        float4 w1 = W4[(k + 1) * 32 + cx];
        float4 w2 = W4[(k + 2) * 32 + cx];
        float4 w3 = W4[(k + 3) * 32 + cx];
#pragma unroll
        for (int j = 0; j < 8; j++) {
            float4 hv = *(const float4*)&xs[ny * 8 + j][k];
            acc[j].x += hv.x * w0.x + hv.y * w1.x + hv.z * w2.x + hv.w * w3.x;
            acc[j].y += hv.x * w0.y + hv.y * w1.y + hv.z * w2.y + hv.w * w3.y;
            acc[j].z += hv.x * w0.z + hv.y * w1.z + hv.z * w2.z + hv.w * w3.z;
            acc[j].w += hv.x * w0.w + hv.y * w1.w + hv.z * w2.w + hv.w * w3.w;
        }
    }
    float4 bc = ((const float4*)b)[cx];
    float4* mg = (float4*)h;
#pragma unroll
    for (int j = 0; j < 8; j++) {
        int n = nbase + ny * 8 + j;
        if (n < NN) {
            float4 o;
            o.x = fmaxf(acc[j].x + bc.x, 0.f);
            o.y = fmaxf(acc[j].y + bc.y, 0.f);
            o.z = fmaxf(acc[j].z + bc.z, 0.f);
            o.w = fmaxf(acc[j].w + bc.w, 0.f);
            mg[n * 32 + cx] = o;
        }
    }
}

// ---------------- per-layer GEMM via MFMA: m(bf16) = h(f32->bf16) @ W_l ----------------
// 4 waves/block, wave = 16 rows x 128 cols. No LDS.
__global__ __launch_bounds__(256) void k_gemm(const float* __restrict__ h,
                                              const ushort* __restrict__ Wp,
                                              ushort* __restrict__ m) {
    int tid = threadIdx.x;
    int w = tid >> 6, l = tid & 63;
    int q = l >> 4, r16 = l & 15;
    int rowbase = blockIdx.x * 64 + w * 16;
    f4v acc[8];
#pragma unroll
    for (int t = 0; t < 8; t++) acc[t] = (f4v){0.f, 0.f, 0.f, 0.f};
    const s8v* wp = (const s8v*)Wp;
#pragma unroll
    for (int kc = 0; kc < 4; kc++) {
        int row = rowbase + r16;
        s8v afrag;
        if (row < NN) {
            const float4* hp = (const float4*)(h + (size_t)row * HID + kc * 32 + q * 8);
            float4 h0 = hp[0], h1 = hp[1];
            afrag[0] = (short)f2bf(h0.x); afrag[1] = (short)f2bf(h0.y);
            afrag[2] = (short)f2bf(h0.z); afrag[3] = (short)f2bf(h0.w);
            afrag[4] = (short)f2bf(h1.x); afrag[5] = (short)f2bf(h1.y);
            afrag[6] = (short)f2bf(h1.z); afrag[7] = (short)f2bf(h1.w);
        } else {
            afrag = (s8v){0, 0, 0, 0, 0, 0, 0, 0};
        }
#pragma unroll
        for (int t = 0; t < 8; t++) {
            s8v bfrag = wp[(kc * 8 + t) * 64 + l];
            acc[t] = __builtin_amdgcn_mfma_f32_16x16x32_bf16(afrag, bfrag, acc[t], 0, 0, 0);
        }
    }
    // C/D layout: col = l&15, row = (l>>4)*4 + reg
#pragma unroll
    for (int t = 0; t < 8; t++) {
#pragma unroll
        for (int rg = 0; rg < 4; rg++) {
            int orow = rowbase + q * 4 + rg;
            if (orow < NN) m[(size_t)orow * HID + t * 16 + r16] = f2bf(acc[t][rg]);
        }
    }
}

// ---------------- aggregate + bias + LN + relu + residual (in-place h) ----------------
// one wave per node, 2 half-waves gather different edges' rows (uint2 = 4 bf16 ch/lane).
// 8 edges/iter from 2 broadcast uint4 record loads.
__global__ __launch_bounds__(256) void k_agg(const ushort* __restrict__ m,
                                             const int* __restrict__ rowp,
                                             const uint* __restrict__ erec,
                                             const float* __restrict__ dinv,
                                             const float* __restrict__ cb,
                                             const float* __restrict__ g,
                                             const float* __restrict__ bb,
                                             float* __restrict__ h) {
    int lane = threadIdx.x & 63;
    int sub = lane & 31;           // channel quad: 4*sub..4*sub+3
    int hi = lane >> 5;            // which edge of the pair
    int n = blockIdx.x * 4 + (threadIdx.x >> 6);
    if (n >= NN) return;
    const uint2* mu2 = (const uint2*)m;
    float dn = dinv[n];
    float selfs = hi ? 0.0f : dn * dn;
    uint2 svu = mu2[(size_t)n * 32 + sub];
    float2 svl = bfu(svu.x), svh = bfu(svu.y);
    float4 a0, a1, a2, a3;
    a0.x = selfs * svl.x; a0.y = selfs * svl.y; a0.z = selfs * svh.x; a0.w = selfs * svh.y;
    a1 = make_float4(0, 0, 0, 0);
    a2 = make_float4(0, 0, 0, 0);
    a3 = make_float4(0, 0, 0, 0);
    int r0 = rowp[n], r1 = rowp[n + 1];          // multiples of 8
    const uint4* e4 = (const uint4*)erec;
    for (int r = r0; r < r1; r += 8) {
        int qb = r >> 2;
        uint4 rA = e4[qb + 0];                   // edges r .. r+3
        uint4 rB = e4[qb + 1];                   // edges r+4 .. r+7
        uint c0 = hi ? rA.y : rA.x;
        uint c1 = hi ? rA.w : rA.z;
        uint c2 = hi ? rB.y : rB.x;
        uint c3 = hi ? rB.w : rB.z;
        int s0 = c0 >> 15;  float v0 = (float)(c0 & 32767u) * (1.0f / VSCALE);
        int s1 = c1 >> 15;  float v1 = (float)(c1 & 32767u) * (1.0f / VSCALE);
        int s2 = c2 >> 15;  float v2 = (float)(c2 & 32767u) * (1.0f / VSCALE);
        int s3 = c3 >> 15;  float v3 = (float)(c3 & 32767u) * (1.0f / VSCALE);
        uint2 g0 = mu2[(size_t)s0 * 32 + sub];
        uint2 g1 = mu2[(size_t)s1 * 32 + sub];
        uint2 g2 = mu2[(size_t)s2 * 32 + sub];
        uint2 g3 = mu2[(size_t)s3 * 32 + sub];
        float2 f0l = bfu(g0.x), f0h = bfu(g0.y);
        float2 f1l = bfu(g1.x), f1h = bfu(g1.y);
        float2 f2l = bfu(g2.x), f2h = bfu(g2.y);
        float2 f3l = bfu(g3.x), f3h = bfu(g3.y);
        a0.x += v0 * f0l.x; a0.y += v0 * f0l.y; a0.z += v0 * f0h.x; a0.w += v0 * f0h.y;
        a1.x += v1 * f1l.x; a1.y += v1 * f1l.y; a1.z += v1 * f1h.x; a1.w += v1 * f1h.y;
        a2.x += v2 * f2l.x; a2.y += v2 * f2l.y; a2.z += v2 * f2h.x; a2.w += v2 * f2h.y;
        a3.x += v3 * f3l.x; a3.y += v3 * f3l.y; a3.z += v3 * f3h.x; a3.w += v3 * f3h.y;
    }
    float4 acc;
    acc.x = a0.x + a1.x + a2.x + a3.x;
    acc.y = a0.y + a1.y + a2.y + a3.y;
    acc.z = a0.z + a1.z + a2.z + a3.z;
    acc.w = a0.w + a1.w + a2.w + a3.w;
    // combine the two half-wave partial sums (lane l <-> l^32)
    acc.x += __shfl_xor(acc.x, 32, 64);
    acc.y += __shfl_xor(acc.y, 32, 64);
    acc.z += __shfl_xor(acc.z, 32, 64);
    acc.w += __shfl_xor(acc.w, 32, 64);
    float4 cbv = ((const float4*)cb)[sub];
    acc.x += cbv.x; acc.y += cbv.y; acc.z += cbv.z; acc.w += cbv.w;
    // LayerNorm over 128 channels: reduce across 32 lanes (both halves identical)
    float s1 = acc.x + acc.y + acc.z + acc.w;
    float s2 = acc.x * acc.x + acc.y * acc.y + acc.z * acc.z + acc.w * acc.w;
#pragma unroll
    for (int off = 16; off > 0; off >>= 1) {
        s1 += __shfl_down(s1, off, 32);
        s2 += __shfl_down(s2, off, 32);
    }
    s1 = __shfl(s1, 0, 32);
    s2 = __shfl(s2, 0, 32);
    float mu = s1 * (1.0f / HID);
    float var = s2 * (1.0f / HID) - mu * mu;
    float rs = rsqrtf(var + LN_EPS);
    if (hi == 0) {
        float4 gv = ((const float4*)g)[sub];
        float4 bv = ((const float4*)bb)[sub];
        float4* h4 = (float4*)h;
        float4 hv = h4[(size_t)n * 32 + sub];
        float4 o;
        o.x = fmaxf((acc.x - mu) * rs * gv.x + bv.x, 0.f) + hv.x;
        o.y = fmaxf((acc.y - mu) * rs * gv.y + bv.y, 0.f) + hv.y;
        o.z = fmaxf((acc.z - mu) * rs * gv.z + bv.z, 0.f) + hv.z;
        o.w = fmaxf((acc.w - mu) * rs * gv.w + bv.w, 0.f) + hv.w;
        h4[(size_t)n * 32 + sub] = o;
    }
}

// ---------------- launch ----------------

extern "C" void kernel_launch(void* const* d_in, const int* in_sizes, int n_in,
                              void* d_out, int out_size, void* d_ws, size_t ws_size,
                              hipStream_t stream) {
    const float* x    = (const float*)d_in[0];
    const int*   ei   = (const int*)d_in[1];
    const float* ew   = (const float*)d_in[2];
    const float* W_in = (const float*)d_in[3];
    const float* b_in = (const float*)d_in[4];
    const float* cW   = (const float*)d_in[5];
    const float* cb   = (const float*)d_in[6];
    const float* lg   = (const float*)d_in[7];
    const float* lb   = (const float*)d_in[8];
    float* h = (float*)d_out;

    char* ws = (char*)d_ws;
    unsigned long long* pk = (unsigned long long*)(ws + 0);   // 50000 u64 (cnt|Q20 deg)
    int*    rowp     = (int*)   (ws + 401408);                // 50001
    int*    rowp_tmp = (int*)   (ws + 602112);
    int*    bsum     = (int*)   (ws + 802816);                // 64
    int*    boff     = (int*)   (ws + 803072);                // 64
    uint*   erec     = (uint*)  (ws + 803328);                // ECAP u32 (4.6 MB)
    float*  dinv     = (float*) (ws + 5403328);               // 50000 f32
    ushort* Wp       = (ushort*)(ws + 5603328);               // 4*16384 bf16 (128 KB)
    ushort* m        = (ushort*)(ws + 5734400);               // 50000*128 bf16 (12.8 MB)
    int*    ord      = (int*)   (ws + 5734400);               // aliases m (dead until gemm)

    const int NB = (NN + 1023) / 1024;                        // 49

    k_zero<<<(100000 / 4 + 255) / 256, 256, 0, stream>>>((int4*)pk, 100000 / 4);
    k_deg_cnt<<<(NE + 255) / 256, 256, 0, stream>>>(ei, ew, pk, ord);
    k_scan_a<<<NB, 1024, 0, stream>>>(pk, rowp_tmp, bsum, dinv);
    k_scan_b<<<1, 64, 0, stream>>>(bsum, boff, rowp, NB);
    k_scan_c<<<NB, 1024, 0, stream>>>(rowp_tmp, boff, rowp);
    k_pad<<<(NN + 255) / 256, 256, 0, stream>>>(pk, rowp, erec);
    k_scatter<<<(NE + 255) / 256, 256, 0, stream>>>(ei, ew, dinv, rowp, ord, erec);
    k_wpack<<<32, 256, 0, stream>>>(cW, Wp);

    k_inproj<<<(NN + 63) / 64, 256, 0, stream>>>(x, W_in, b_in, h);

    for (int l = 0; l < NL; l++) {
        k_gemm<<<(NN + 63) / 64, 256, 0, stream>>>(h, Wp + (size_t)l * 16384, m);
        k_agg<<<(NN + 3) / 4, 256, 0, stream>>>(m, rowp, erec, dinv,
                                                cb + l * HID, lg + l * HID, lb + l * HID, h);
    }
}